// Round 1
// baseline (608.926 us; speedup 1.0000x reference)
//
#include <hip/hip_runtime.h>

#define NFEAT 128

static inline size_t align_up(size_t x, size_t a) { return (x + a - 1) & ~(a - 1); }

// ---------------- preprocessing: degree, rsqrt, CSR build ----------------

__global__ __launch_bounds__(256) void k_zero(int* p, int n) {
  int i = blockIdx.x * 256 + threadIdx.x;
  if (i < n) p[i] = 0;
}

__global__ __launch_bounds__(256) void k_count(const int* __restrict__ dst,
                                               int* __restrict__ cnt, int E) {
  int e = blockIdx.x * 256 + threadIdx.x;
  if (e < E) atomicAdd(&cnt[dst[e]], 1);
}

__global__ __launch_bounds__(256) void k_dis(const int* __restrict__ cnt,
                                             float* __restrict__ dis, int N) {
  int i = blockIdx.x * 256 + threadIdx.x;
  if (i < N) dis[i] = rsqrtf((float)cnt[i] + 1.0f);  // deg = in_deg + self loop
}

// block-level exclusive scan, 1024 items/block (256 thr x 4)
__global__ __launch_bounds__(256) void k_scan1(const int* __restrict__ cnt,
                                               int* __restrict__ rs,
                                               int* __restrict__ bsums, int N) {
  __shared__ int sd[256];
  int tid = threadIdx.x;
  int base = blockIdx.x * 1024 + tid * 4;
  int v0 = 0, v1 = 0, v2 = 0, v3 = 0;
  if (base + 0 < N) v0 = cnt[base + 0];
  if (base + 1 < N) v1 = cnt[base + 1];
  if (base + 2 < N) v2 = cnt[base + 2];
  if (base + 3 < N) v3 = cnt[base + 3];
  int sum = v0 + v1 + v2 + v3;
  sd[tid] = sum;
  __syncthreads();
  for (int off = 1; off < 256; off <<= 1) {
    int t = (tid >= off) ? sd[tid - off] : 0;
    __syncthreads();
    sd[tid] += t;
    __syncthreads();
  }
  int run = sd[tid] - sum;  // exclusive prefix for this thread
  if (tid == 255) bsums[blockIdx.x] = sd[255];
  if (base + 0 < N) rs[base + 0] = run;
  run += v0;
  if (base + 1 < N) rs[base + 1] = run;
  run += v1;
  if (base + 2 < N) rs[base + 2] = run;
  run += v2;
  if (base + 3 < N) rs[base + 3] = run;
}

// scan of block sums (nb <= 128)
__global__ __launch_bounds__(128) void k_scan2(int* bsums, int nb) {
  __shared__ int sd[128];
  int tid = threadIdx.x;
  int v = (tid < nb) ? bsums[tid] : 0;
  sd[tid] = v;
  __syncthreads();
  for (int off = 1; off < 128; off <<= 1) {
    int t = (tid >= off) ? sd[tid - off] : 0;
    __syncthreads();
    sd[tid] += t;
    __syncthreads();
  }
  if (tid < nb) bsums[tid] = sd[tid] - v;  // exclusive
}

__global__ __launch_bounds__(256) void k_scan3(int* __restrict__ rs,
                                               const int* __restrict__ bsums,
                                               int* __restrict__ cnt, int N, int E) {
  int i = blockIdx.x * 256 + threadIdx.x;
  if (i < N) {
    rs[i] += bsums[i >> 10];
    cnt[i] = 0;  // reuse as fill cursor
  }
  if (i == 0) rs[N] = E;
}

__global__ __launch_bounds__(256) void k_fill(const int* __restrict__ src,
                                              const int* __restrict__ dst,
                                              const int* __restrict__ rs,
                                              int* __restrict__ cnt,
                                              const float* __restrict__ dis,
                                              int* __restrict__ csrc,
                                              float* __restrict__ cw, int E) {
  int e = blockIdx.x * 256 + threadIdx.x;
  if (e >= E) return;
  int d = dst[e];
  int s = src[e];
  int pos = rs[d] + atomicAdd(&cnt[d], 1);
  csrc[pos] = s;
  cw[pos] = dis[s];  // multiply by dis[dst] at aggregation time
}

// ---------------- GEMM: C[N x128] = X[N x128] @ W[128 x128] (row-major) ----------------
// 64-row tile, W staged in two 64-row K-halves -> 65KB LDS -> 2 blocks/CU.
// Thread tile: 4 rows x 8 cols.

__global__ __launch_bounds__(256) void k_gemm(const float* __restrict__ X,
                                              const float* __restrict__ W,
                                              float* __restrict__ C, int N) {
  __shared__ float Xs[64][132];   // +4 pad: x-column reads land on distinct banks
  __shared__ float Ws[64][128];
  const int tid = threadIdx.x;
  const int rowBase = blockIdx.x * 64;

  // stage X tile (64 x 128), zero-fill out-of-range rows
  #pragma unroll
  for (int it = 0; it < 8; ++it) {
    int q = it * 256 + tid;      // float4 id, 2048 total
    int r = q >> 5;
    int c = (q & 31) * 4;
    int gr = rowBase + r;
    float4 v = make_float4(0.f, 0.f, 0.f, 0.f);
    if (gr < N) v = *(const float4*)(X + (size_t)gr * NFEAT + c);
    *(float4*)&Xs[r][c] = v;
  }

  float acc[4][8];
  #pragma unroll
  for (int j = 0; j < 4; ++j)
    #pragma unroll
    for (int c = 0; c < 8; ++c) acc[j][c] = 0.f;

  const int cx = (tid & 15) * 8;
  const int r0 = (tid >> 4) * 4;

  for (int half = 0; half < 2; ++half) {
    __syncthreads();  // Xs staged / previous compute done before Ws overwrite
    #pragma unroll
    for (int it = 0; it < 8; ++it) {
      int q = it * 256 + tid;
      int r = q >> 5;
      int c = (q & 31) * 4;
      *(float4*)&Ws[r][c] = *(const float4*)(W + (size_t)(half * 64 + r) * NFEAT + c);
    }
    __syncthreads();
    #pragma unroll 4
    for (int k = 0; k < 64; ++k) {
      float4 w0 = *(const float4*)&Ws[k][cx];
      float4 w1 = *(const float4*)&Ws[k][cx + 4];
      int kg = half * 64 + k;
      #pragma unroll
      for (int j = 0; j < 4; ++j) {
        float xv = Xs[r0 + j][kg];
        acc[j][0] = fmaf(xv, w0.x, acc[j][0]);
        acc[j][1] = fmaf(xv, w0.y, acc[j][1]);
        acc[j][2] = fmaf(xv, w0.z, acc[j][2]);
        acc[j][3] = fmaf(xv, w0.w, acc[j][3]);
        acc[j][4] = fmaf(xv, w1.x, acc[j][4]);
        acc[j][5] = fmaf(xv, w1.y, acc[j][5]);
        acc[j][6] = fmaf(xv, w1.z, acc[j][6]);
        acc[j][7] = fmaf(xv, w1.w, acc[j][7]);
      }
    }
  }

  #pragma unroll
  for (int j = 0; j < 4; ++j) {
    int gr = rowBase + r0 + j;
    if (gr < N) {
      float4 o0 = make_float4(acc[j][0], acc[j][1], acc[j][2], acc[j][3]);
      float4 o1 = make_float4(acc[j][4], acc[j][5], acc[j][6], acc[j][7]);
      *(float4*)(C + (size_t)gr * NFEAT + cx) = o0;
      *(float4*)(C + (size_t)gr * NFEAT + cx + 4) = o1;
    }
  }
}

// ---------------- aggregation: one wave per node, lane holds 2 features ----------------

__global__ __launch_bounds__(256) void k_agg_relu(const float* __restrict__ H,
                                                  const int* __restrict__ rs,
                                                  const int* __restrict__ csrc,
                                                  const float* __restrict__ cw,
                                                  const float* __restrict__ dis,
                                                  const float* __restrict__ bias,
                                                  float* __restrict__ Hout, int N) {
  int w = (blockIdx.x * 256 + threadIdx.x) >> 6;
  int lane = threadIdx.x & 63;
  if (w >= N) return;
  float di = dis[w];
  float2 h = ((const float2*)(H + (size_t)w * NFEAT))[lane];
  float sw = di * di;  // self-loop norm
  float ax = h.x * sw, ay = h.y * sw;
  int e0 = rs[w], e1 = rs[w + 1];
  for (int e = e0; e < e1; ++e) {
    int s = csrc[e];
    float wt = cw[e] * di;
    float2 hv = ((const float2*)(H + (size_t)s * NFEAT))[lane];
    ax = fmaf(hv.x, wt, ax);
    ay = fmaf(hv.y, wt, ay);
  }
  float2 b = ((const float2*)bias)[lane];
  float2 r;
  r.x = fmaxf(ax + b.x, 0.f);
  r.y = fmaxf(ay + b.y, 0.f);
  ((float2*)(Hout + (size_t)w * NFEAT))[lane] = r;
}

__global__ __launch_bounds__(256) void k_agg_readout(const float* __restrict__ H,
                                                     const int* __restrict__ rs,
                                                     const int* __restrict__ csrc,
                                                     const float* __restrict__ cw,
                                                     const float* __restrict__ dis,
                                                     const float* __restrict__ bias,
                                                     const float* __restrict__ Wout,
                                                     const float* __restrict__ bout,
                                                     float* __restrict__ out, int N) {
  int w = (blockIdx.x * 256 + threadIdx.x) >> 6;
  int lane = threadIdx.x & 63;
  if (w >= N) return;
  float di = dis[w];
  float2 h = ((const float2*)(H + (size_t)w * NFEAT))[lane];
  float sw = di * di;
  float ax = h.x * sw, ay = h.y * sw;
  int e0 = rs[w], e1 = rs[w + 1];
  for (int e = e0; e < e1; ++e) {
    int s = csrc[e];
    float wt = cw[e] * di;
    float2 hv = ((const float2*)(H + (size_t)s * NFEAT))[lane];
    ax = fmaf(hv.x, wt, ax);
    ay = fmaf(hv.y, wt, ay);
  }
  float2 b = ((const float2*)bias)[lane];
  float2 wo = ((const float2*)Wout)[lane];
  float v = fmaxf(ax + b.x, 0.f) * wo.x + fmaxf(ay + b.y, 0.f) * wo.y;
  #pragma unroll
  for (int off = 32; off > 0; off >>= 1) v += __shfl_down(v, off, 64);
  if (lane == 0) out[w] = v + bout[0];
}

// ---------------- launch ----------------

extern "C" void kernel_launch(void* const* d_in, const int* in_sizes, int n_in,
                              void* d_out, int out_size, void* d_ws, size_t ws_size,
                              hipStream_t stream) {
  const float* x    = (const float*)d_in[0];
  const int*   ei   = (const int*)d_in[1];
  const float* W1   = (const float*)d_in[2];
  const float* b1   = (const float*)d_in[3];
  const float* W2   = (const float*)d_in[4];
  const float* b2   = (const float*)d_in[5];
  const float* Wout = (const float*)d_in[6];
  const float* bout = (const float*)d_in[7];
  float* out = (float*)d_out;

  const int N = in_sizes[0] / NFEAT;
  const int E = in_sizes[1] / 2;
  const int* src = ei;
  const int* dst = ei + E;

  char* ws = (char*)d_ws;
  size_t off = 0;
  auto alloc = [&](size_t bytes) -> char* {
    char* p = ws + off;
    off = align_up(off + bytes, 256);
    return p;
  };
  float* dis   = (float*)alloc((size_t)N * 4);
  int*   cnt   = (int*)alloc((size_t)N * 4);
  int*   rs    = (int*)alloc((size_t)(N + 1) * 4);
  int*   bsums = (int*)alloc(1024 * 4);
  int*   csrc  = (int*)alloc((size_t)E * 4);
  float* cw    = (float*)alloc((size_t)E * 4);
  float* bufA  = (float*)alloc((size_t)N * NFEAT * 4);
  float* bufB  = (float*)alloc((size_t)N * NFEAT * 4);
  (void)ws_size; (void)n_in; (void)out_size;

  const int nbN = (N + 255) / 256;
  const int nbE = (E + 255) / 256;
  const int nbS = (N + 1023) / 1024;  // 98 for N=100000 (<=128 for k_scan2)

  k_zero<<<nbN, 256, 0, stream>>>(cnt, N);
  k_count<<<nbE, 256, 0, stream>>>(dst, cnt, E);
  k_dis<<<nbN, 256, 0, stream>>>(cnt, dis, N);
  k_scan1<<<nbS, 256, 0, stream>>>(cnt, rs, bsums, N);
  k_scan2<<<1, 128, 0, stream>>>(bsums, nbS);
  k_scan3<<<nbN, 256, 0, stream>>>(rs, bsums, cnt, N, E);
  k_fill<<<nbE, 256, 0, stream>>>(src, dst, rs, cnt, dis, csrc, cw, E);

  k_gemm<<<(N + 63) / 64, 256, 0, stream>>>(x, W1, bufA, N);
  k_agg_relu<<<(N + 3) / 4, 256, 0, stream>>>(bufA, rs, csrc, cw, dis, b1, bufB, N);
  k_gemm<<<(N + 63) / 64, 256, 0, stream>>>(bufB, W2, bufA, N);
  k_agg_readout<<<(N + 3) / 4, 256, 0, stream>>>(bufA, rs, csrc, cw, dis, b2, Wout, bout, out, N);
}

// Round 2
// 574.509 us; speedup vs baseline: 1.0599x; 1.0599x over previous
//
#include <hip/hip_runtime.h>
#include <hip/hip_fp16.h>

#define NFEAT 128

static inline size_t align_up(size_t x, size_t a) { return (x + a - 1) & ~(a - 1); }

// ---------------- preprocessing: degree, rsqrt, CSR build ----------------

__global__ __launch_bounds__(256) void k_count(const int* __restrict__ dst,
                                               int* __restrict__ cnt, int E) {
  int e = blockIdx.x * 256 + threadIdx.x;
  if (e < E) atomicAdd(&cnt[dst[e]], 1);
}

// block-level exclusive scan, 1024 items/block (256 thr x 4); also emits dis = rsqrt(deg)
__global__ __launch_bounds__(256) void k_scan1(const int* __restrict__ cnt,
                                               int* __restrict__ rs,
                                               int* __restrict__ bsums,
                                               float* __restrict__ dis, int N) {
  __shared__ int sd[256];
  int tid = threadIdx.x;
  int base = blockIdx.x * 1024 + tid * 4;
  int v0 = 0, v1 = 0, v2 = 0, v3 = 0;
  if (base + 0 < N) v0 = cnt[base + 0];
  if (base + 1 < N) v1 = cnt[base + 1];
  if (base + 2 < N) v2 = cnt[base + 2];
  if (base + 3 < N) v3 = cnt[base + 3];
  if (base + 0 < N) dis[base + 0] = rsqrtf((float)v0 + 1.0f);
  if (base + 1 < N) dis[base + 1] = rsqrtf((float)v1 + 1.0f);
  if (base + 2 < N) dis[base + 2] = rsqrtf((float)v2 + 1.0f);
  if (base + 3 < N) dis[base + 3] = rsqrtf((float)v3 + 1.0f);
  int sum = v0 + v1 + v2 + v3;
  sd[tid] = sum;
  __syncthreads();
  for (int off = 1; off < 256; off <<= 1) {
    int t = (tid >= off) ? sd[tid - off] : 0;
    __syncthreads();
    sd[tid] += t;
    __syncthreads();
  }
  int run = sd[tid] - sum;  // exclusive prefix for this thread
  if (tid == 255) bsums[blockIdx.x] = sd[255];
  if (base + 0 < N) rs[base + 0] = run;
  run += v0;
  if (base + 1 < N) rs[base + 1] = run;
  run += v1;
  if (base + 2 < N) rs[base + 2] = run;
  run += v2;
  if (base + 3 < N) rs[base + 3] = run;
}

// scan of block sums (nb <= 128)
__global__ __launch_bounds__(128) void k_scan2(int* bsums, int nb) {
  __shared__ int sd[128];
  int tid = threadIdx.x;
  int v = (tid < nb) ? bsums[tid] : 0;
  sd[tid] = v;
  __syncthreads();
  for (int off = 1; off < 128; off <<= 1) {
    int t = (tid >= off) ? sd[tid - off] : 0;
    __syncthreads();
    sd[tid] += t;
    __syncthreads();
  }
  if (tid < nb) bsums[tid] = sd[tid] - v;  // exclusive
}

__global__ __launch_bounds__(256) void k_scan3(int* __restrict__ rs,
                                               const int* __restrict__ bsums,
                                               int* __restrict__ cnt, int N, int E) {
  int i = blockIdx.x * 256 + threadIdx.x;
  if (i < N) {
    rs[i] += bsums[i >> 10];
    cnt[i] = 0;  // reuse as fill cursor
  }
  if (i == 0) rs[N] = E;
}

__global__ __launch_bounds__(256) void k_fill(const int* __restrict__ src,
                                              const int* __restrict__ dst,
                                              const int* __restrict__ rs,
                                              int* __restrict__ cnt,
                                              const float* __restrict__ dis,
                                              int* __restrict__ csrc,
                                              float* __restrict__ cw, int E) {
  int e = blockIdx.x * 256 + threadIdx.x;
  if (e >= E) return;
  int d = dst[e];
  int s = src[e];
  int pos = rs[d] + atomicAdd(&cnt[d], 1);
  csrc[pos] = s;
  cw[pos] = dis[s];  // multiply by dis[dst] at aggregation time
}

// ---------------- GEMM: P[N x128] = X[N x128] @ W[128 x128], fp32 in, fp16 out ----------------
// 64-row tile, W staged in two 64-row K-halves. Thread tile: 4 rows x 8 cols.

__global__ __launch_bounds__(256) void k_gemm(const float* __restrict__ X,
                                              const float* __restrict__ W,
                                              __half* __restrict__ P, int N) {
  __shared__ float Xs[64][132];   // +4 pad
  __shared__ float Ws[64][128];
  const int tid = threadIdx.x;
  const int rowBase = blockIdx.x * 64;

  #pragma unroll
  for (int it = 0; it < 8; ++it) {
    int q = it * 256 + tid;
    int r = q >> 5;
    int c = (q & 31) * 4;
    int gr = rowBase + r;
    float4 v = make_float4(0.f, 0.f, 0.f, 0.f);
    if (gr < N) v = *(const float4*)(X + (size_t)gr * NFEAT + c);
    *(float4*)&Xs[r][c] = v;
  }

  float acc[4][8];
  #pragma unroll
  for (int j = 0; j < 4; ++j)
    #pragma unroll
    for (int c = 0; c < 8; ++c) acc[j][c] = 0.f;

  const int cx = (tid & 15) * 8;
  const int r0 = (tid >> 4) * 4;

  for (int half = 0; half < 2; ++half) {
    __syncthreads();
    #pragma unroll
    for (int it = 0; it < 8; ++it) {
      int q = it * 256 + tid;
      int r = q >> 5;
      int c = (q & 31) * 4;
      *(float4*)&Ws[r][c] = *(const float4*)(W + (size_t)(half * 64 + r) * NFEAT + c);
    }
    __syncthreads();
    #pragma unroll 4
    for (int k = 0; k < 64; ++k) {
      float4 w0 = *(const float4*)&Ws[k][cx];
      float4 w1 = *(const float4*)&Ws[k][cx + 4];
      int kg = half * 64 + k;
      #pragma unroll
      for (int j = 0; j < 4; ++j) {
        float xv = Xs[r0 + j][kg];
        acc[j][0] = fmaf(xv, w0.x, acc[j][0]);
        acc[j][1] = fmaf(xv, w0.y, acc[j][1]);
        acc[j][2] = fmaf(xv, w0.z, acc[j][2]);
        acc[j][3] = fmaf(xv, w0.w, acc[j][3]);
        acc[j][4] = fmaf(xv, w1.x, acc[j][4]);
        acc[j][5] = fmaf(xv, w1.y, acc[j][5]);
        acc[j][6] = fmaf(xv, w1.z, acc[j][6]);
        acc[j][7] = fmaf(xv, w1.w, acc[j][7]);
      }
    }
  }

  #pragma unroll
  for (int j = 0; j < 4; ++j) {
    int gr = rowBase + r0 + j;
    if (gr < N) {
      __half2 o[4];
      o[0] = __floats2half2_rn(acc[j][0], acc[j][1]);
      o[1] = __floats2half2_rn(acc[j][2], acc[j][3]);
      o[2] = __floats2half2_rn(acc[j][4], acc[j][5]);
      o[3] = __floats2half2_rn(acc[j][6], acc[j][7]);
      *(int4*)(P + (size_t)gr * NFEAT + cx) = *(const int4*)o;  // 8 halves = 16B
    }
  }
}

// ---------------- aggregation: one wave per node, lane holds 2 features (fp16 gather) ----------------

__global__ __launch_bounds__(256) void k_agg_relu(const __half* __restrict__ P,
                                                  const int* __restrict__ rs,
                                                  const int* __restrict__ csrc,
                                                  const float* __restrict__ cw,
                                                  const float* __restrict__ dis,
                                                  const float* __restrict__ bias,
                                                  float* __restrict__ Hout, int N) {
  int w = (blockIdx.x * 256 + threadIdx.x) >> 6;
  int lane = threadIdx.x & 63;
  if (w >= N) return;
  float di = dis[w];
  float2 h = __half22float2(((const __half2*)(P + (size_t)w * NFEAT))[lane]);
  float sw = di * di;  // self-loop norm
  float ax = h.x * sw, ay = h.y * sw;
  int e0 = rs[w], e1 = rs[w + 1];
  for (int e = e0; e < e1; ++e) {
    int s = csrc[e];
    float wt = cw[e] * di;
    float2 hv = __half22float2(((const __half2*)(P + (size_t)s * NFEAT))[lane]);
    ax = fmaf(hv.x, wt, ax);
    ay = fmaf(hv.y, wt, ay);
  }
  float2 b = ((const float2*)bias)[lane];
  float2 r;
  r.x = fmaxf(ax + b.x, 0.f);
  r.y = fmaxf(ay + b.y, 0.f);
  ((float2*)(Hout + (size_t)w * NFEAT))[lane] = r;
}

__global__ __launch_bounds__(256) void k_agg_readout(const __half* __restrict__ P,
                                                     const int* __restrict__ rs,
                                                     const int* __restrict__ csrc,
                                                     const float* __restrict__ cw,
                                                     const float* __restrict__ dis,
                                                     const float* __restrict__ bias,
                                                     const float* __restrict__ Wout,
                                                     const float* __restrict__ bout,
                                                     float* __restrict__ out, int N) {
  int w = (blockIdx.x * 256 + threadIdx.x) >> 6;
  int lane = threadIdx.x & 63;
  if (w >= N) return;
  float di = dis[w];
  float2 h = __half22float2(((const __half2*)(P + (size_t)w * NFEAT))[lane]);
  float sw = di * di;
  float ax = h.x * sw, ay = h.y * sw;
  int e0 = rs[w], e1 = rs[w + 1];
  for (int e = e0; e < e1; ++e) {
    int s = csrc[e];
    float wt = cw[e] * di;
    float2 hv = __half22float2(((const __half2*)(P + (size_t)s * NFEAT))[lane]);
    ax = fmaf(hv.x, wt, ax);
    ay = fmaf(hv.y, wt, ay);
  }
  float2 b = ((const float2*)bias)[lane];
  float2 wo = ((const float2*)Wout)[lane];
  float v = fmaxf(ax + b.x, 0.f) * wo.x + fmaxf(ay + b.y, 0.f) * wo.y;
  #pragma unroll
  for (int off = 32; off > 0; off >>= 1) v += __shfl_down(v, off, 64);
  if (lane == 0) out[w] = v + bout[0];
}

// ---------------- launch ----------------

extern "C" void kernel_launch(void* const* d_in, const int* in_sizes, int n_in,
                              void* d_out, int out_size, void* d_ws, size_t ws_size,
                              hipStream_t stream) {
  const float* x    = (const float*)d_in[0];
  const int*   ei   = (const int*)d_in[1];
  const float* W1   = (const float*)d_in[2];
  const float* b1   = (const float*)d_in[3];
  const float* W2   = (const float*)d_in[4];
  const float* b2   = (const float*)d_in[5];
  const float* Wout = (const float*)d_in[6];
  const float* bout = (const float*)d_in[7];
  float* out = (float*)d_out;

  const int N = in_sizes[0] / NFEAT;
  const int E = in_sizes[1] / 2;
  const int* src = ei;
  const int* dst = ei + E;

  char* ws = (char*)d_ws;
  size_t off = 0;
  auto alloc = [&](size_t bytes) -> char* {
    char* p = ws + off;
    off = align_up(off + bytes, 256);
    return p;
  };
  float*  dis   = (float*)alloc((size_t)N * 4);
  int*    cnt   = (int*)alloc((size_t)N * 4);
  int*    rs    = (int*)alloc((size_t)(N + 1) * 4);
  int*    bsums = (int*)alloc(1024 * 4);
  int*    csrc  = (int*)alloc((size_t)E * 4);
  float*  cw    = (float*)alloc((size_t)E * 4);
  __half* P     = (__half*)alloc((size_t)N * NFEAT * 2);   // fp16 gather operand
  float*  H     = (float*)alloc((size_t)N * NFEAT * 4);    // fp32 hidden (gemm input)
  (void)ws_size; (void)n_in; (void)out_size;

  const int nbN = (N + 255) / 256;
  const int nbE = (E + 255) / 256;
  const int nbS = (N + 1023) / 1024;  // 98 for N=100000 (<=128 for k_scan2)

  hipMemsetAsync(cnt, 0, (size_t)N * 4, stream);
  k_count<<<nbE, 256, 0, stream>>>(dst, cnt, E);
  k_scan1<<<nbS, 256, 0, stream>>>(cnt, rs, bsums, dis, N);
  k_scan2<<<1, 128, 0, stream>>>(bsums, nbS);
  k_scan3<<<nbN, 256, 0, stream>>>(rs, bsums, cnt, N, E);
  k_fill<<<nbE, 256, 0, stream>>>(src, dst, rs, cnt, dis, csrc, cw, E);

  k_gemm<<<(N + 63) / 64, 256, 0, stream>>>(x, W1, P, N);
  k_agg_relu<<<(N + 3) / 4, 256, 0, stream>>>(P, rs, csrc, cw, dis, b1, H, N);
  k_gemm<<<(N + 63) / 64, 256, 0, stream>>>(H, W2, P, N);
  k_agg_readout<<<(N + 3) / 4, 256, 0, stream>>>(P, rs, csrc, cw, dis, b2, Wout, bout, out, N);
}

// Round 3
// 439.935 us; speedup vs baseline: 1.3841x; 1.3059x over previous
//
#include <hip/hip_runtime.h>
#include <hip/hip_fp16.h>

#define NFEAT 128

static inline size_t align_up(size_t x, size_t a) { return (x + a - 1) & ~(a - 1); }

// ---------------- preprocessing: degree, rsqrt, CSR build ----------------

__global__ __launch_bounds__(256) void k_count(const int* __restrict__ dst,
                                               int* __restrict__ cnt, int E) {
  int e = blockIdx.x * 256 + threadIdx.x;
  if (e < E) atomicAdd(&cnt[dst[e]], 1);
}

// block-level exclusive scan, 1024 items/block (256 thr x 4); also emits dis = rsqrt(deg)
__global__ __launch_bounds__(256) void k_scan1(const int* __restrict__ cnt,
                                               int* __restrict__ rs,
                                               int* __restrict__ bsums,
                                               float* __restrict__ dis, int N) {
  __shared__ int sd[256];
  int tid = threadIdx.x;
  int base = blockIdx.x * 1024 + tid * 4;
  int v0 = 0, v1 = 0, v2 = 0, v3 = 0;
  if (base + 0 < N) v0 = cnt[base + 0];
  if (base + 1 < N) v1 = cnt[base + 1];
  if (base + 2 < N) v2 = cnt[base + 2];
  if (base + 3 < N) v3 = cnt[base + 3];
  if (base + 0 < N) dis[base + 0] = rsqrtf((float)v0 + 1.0f);
  if (base + 1 < N) dis[base + 1] = rsqrtf((float)v1 + 1.0f);
  if (base + 2 < N) dis[base + 2] = rsqrtf((float)v2 + 1.0f);
  if (base + 3 < N) dis[base + 3] = rsqrtf((float)v3 + 1.0f);
  int sum = v0 + v1 + v2 + v3;
  sd[tid] = sum;
  __syncthreads();
  for (int off = 1; off < 256; off <<= 1) {
    int t = (tid >= off) ? sd[tid - off] : 0;
    __syncthreads();
    sd[tid] += t;
    __syncthreads();
  }
  int run = sd[tid] - sum;  // exclusive prefix for this thread
  if (tid == 255) bsums[blockIdx.x] = sd[255];
  if (base + 0 < N) rs[base + 0] = run;
  run += v0;
  if (base + 1 < N) rs[base + 1] = run;
  run += v1;
  if (base + 2 < N) rs[base + 2] = run;
  run += v2;
  if (base + 3 < N) rs[base + 3] = run;
}

// scan of block sums (nb <= 128)
__global__ __launch_bounds__(128) void k_scan2(int* bsums, int nb) {
  __shared__ int sd[128];
  int tid = threadIdx.x;
  int v = (tid < nb) ? bsums[tid] : 0;
  sd[tid] = v;
  __syncthreads();
  for (int off = 1; off < 128; off <<= 1) {
    int t = (tid >= off) ? sd[tid - off] : 0;
    __syncthreads();
    sd[tid] += t;
    __syncthreads();
  }
  if (tid < nb) bsums[tid] = sd[tid] - v;  // exclusive
}

__global__ __launch_bounds__(256) void k_scan3(int* __restrict__ rs,
                                               const int* __restrict__ bsums,
                                               int* __restrict__ cnt, int N, int E) {
  int i = blockIdx.x * 256 + threadIdx.x;
  if (i < N) {
    rs[i] += bsums[i >> 10];
    cnt[i] = 0;  // reuse as fill cursor
  }
  if (i == 0) rs[N] = E;
}

__global__ __launch_bounds__(256) void k_fill(const int* __restrict__ src,
                                              const int* __restrict__ dst,
                                              const int* __restrict__ rs,
                                              int* __restrict__ cnt,
                                              const float* __restrict__ dis,
                                              int* __restrict__ csrc,
                                              float* __restrict__ cw, int E) {
  int e = blockIdx.x * 256 + threadIdx.x;
  if (e >= E) return;
  int d = dst[e];
  int s = src[e];
  int pos = rs[d] + atomicAdd(&cnt[d], 1);
  csrc[pos] = s;
  cw[pos] = dis[s];  // multiply by dis[dst] at aggregation time
}

// ---------------- GEMM: P[N x128] = X[N x128] @ W[128 x128], fp32 in, fp16 out ----------------

__global__ __launch_bounds__(256) void k_gemm(const float* __restrict__ X,
                                              const float* __restrict__ W,
                                              __half* __restrict__ P, int N) {
  __shared__ float Xs[64][132];   // +4 pad
  __shared__ float Ws[64][128];
  const int tid = threadIdx.x;
  const int rowBase = blockIdx.x * 64;

  #pragma unroll
  for (int it = 0; it < 8; ++it) {
    int q = it * 256 + tid;
    int r = q >> 5;
    int c = (q & 31) * 4;
    int gr = rowBase + r;
    float4 v = make_float4(0.f, 0.f, 0.f, 0.f);
    if (gr < N) v = *(const float4*)(X + (size_t)gr * NFEAT + c);
    *(float4*)&Xs[r][c] = v;
  }

  float acc[4][8];
  #pragma unroll
  for (int j = 0; j < 4; ++j)
    #pragma unroll
    for (int c = 0; c < 8; ++c) acc[j][c] = 0.f;

  const int cx = (tid & 15) * 8;
  const int r0 = (tid >> 4) * 4;

  for (int half = 0; half < 2; ++half) {
    __syncthreads();
    #pragma unroll
    for (int it = 0; it < 8; ++it) {
      int q = it * 256 + tid;
      int r = q >> 5;
      int c = (q & 31) * 4;
      *(float4*)&Ws[r][c] = *(const float4*)(W + (size_t)(half * 64 + r) * NFEAT + c);
    }
    __syncthreads();
    #pragma unroll 4
    for (int k = 0; k < 64; ++k) {
      float4 w0 = *(const float4*)&Ws[k][cx];
      float4 w1 = *(const float4*)&Ws[k][cx + 4];
      int kg = half * 64 + k;
      #pragma unroll
      for (int j = 0; j < 4; ++j) {
        float xv = Xs[r0 + j][kg];
        acc[j][0] = fmaf(xv, w0.x, acc[j][0]);
        acc[j][1] = fmaf(xv, w0.y, acc[j][1]);
        acc[j][2] = fmaf(xv, w0.z, acc[j][2]);
        acc[j][3] = fmaf(xv, w0.w, acc[j][3]);
        acc[j][4] = fmaf(xv, w1.x, acc[j][4]);
        acc[j][5] = fmaf(xv, w1.y, acc[j][5]);
        acc[j][6] = fmaf(xv, w1.z, acc[j][6]);
        acc[j][7] = fmaf(xv, w1.w, acc[j][7]);
      }
    }
  }

  #pragma unroll
  for (int j = 0; j < 4; ++j) {
    int gr = rowBase + r0 + j;
    if (gr < N) {
      __half2 o[4];
      o[0] = __floats2half2_rn(acc[j][0], acc[j][1]);
      o[1] = __floats2half2_rn(acc[j][2], acc[j][3]);
      o[2] = __floats2half2_rn(acc[j][4], acc[j][5]);
      o[3] = __floats2half2_rn(acc[j][6], acc[j][7]);
      *(int4*)(P + (size_t)gr * NFEAT + cx) = *(const int4*)o;  // 8 halves = 16B
    }
  }
}

// ---------------- aggregation: one wave/node, 4 edge-groups x 16 lanes, 16B/lane ----------------
// Lane layout: g = lane>>4 (edge group), li = lane&15 (feature block: 8 halves = 16B).
// Per iteration the wave gathers 4 rows (1024B) with ONE dwordx4 instruction.

__device__ __forceinline__ void agg_body(const __half* __restrict__ P,
                                         const int* __restrict__ rs,
                                         const int* __restrict__ csrc,
                                         const float* __restrict__ cw,
                                         float di, int w, int g, int li,
                                         float acc[8]) {
  // self-loop: group 0 reads own row, scaled by di*di
  if (g == 0) {
    float sw = di * di;
    int4 raw = *(const int4*)(P + (size_t)w * NFEAT + li * 8);
    const __half2* h2 = (const __half2*)&raw;
    #pragma unroll
    for (int j = 0; j < 4; ++j) {
      float2 f = __half22float2(h2[j]);
      acc[2 * j]     = f.x * sw;
      acc[2 * j + 1] = f.y * sw;
    }
  }
  int e0 = rs[w], e1 = rs[w + 1];
  for (int e = e0 + g; e < e1; e += 4) {
    int s = csrc[e];
    float wt = cw[e] * di;
    int4 raw = *(const int4*)(P + (size_t)s * NFEAT + li * 8);
    const __half2* h2 = (const __half2*)&raw;
    #pragma unroll
    for (int j = 0; j < 4; ++j) {
      float2 f = __half22float2(h2[j]);
      acc[2 * j]     = fmaf(f.x, wt, acc[2 * j]);
      acc[2 * j + 1] = fmaf(f.y, wt, acc[2 * j + 1]);
    }
  }
  // combine the 4 edge-groups: lanes with equal (lane&15) sum up
  #pragma unroll
  for (int j = 0; j < 8; ++j) {
    float v = acc[j];
    v += __shfl_xor(v, 16, 64);
    v += __shfl_xor(v, 32, 64);
    acc[j] = v;
  }
}

__global__ __launch_bounds__(256) void k_agg_relu(const __half* __restrict__ P,
                                                  const int* __restrict__ rs,
                                                  const int* __restrict__ csrc,
                                                  const float* __restrict__ cw,
                                                  const float* __restrict__ dis,
                                                  const float* __restrict__ bias,
                                                  float* __restrict__ Hout, int N) {
  int w = (blockIdx.x * 256 + threadIdx.x) >> 6;
  if (w >= N) return;
  int lane = threadIdx.x & 63;
  int g = lane >> 4, li = lane & 15;
  float di = dis[w];
  float acc[8] = {0, 0, 0, 0, 0, 0, 0, 0};
  agg_body(P, rs, csrc, cw, di, w, g, li, acc);
  if (g == 0) {
    float4 b0 = *(const float4*)(bias + li * 8);
    float4 b1 = *(const float4*)(bias + li * 8 + 4);
    float4 o0, o1;
    o0.x = fmaxf(acc[0] + b0.x, 0.f);
    o0.y = fmaxf(acc[1] + b0.y, 0.f);
    o0.z = fmaxf(acc[2] + b0.z, 0.f);
    o0.w = fmaxf(acc[3] + b0.w, 0.f);
    o1.x = fmaxf(acc[4] + b1.x, 0.f);
    o1.y = fmaxf(acc[5] + b1.y, 0.f);
    o1.z = fmaxf(acc[6] + b1.z, 0.f);
    o1.w = fmaxf(acc[7] + b1.w, 0.f);
    *(float4*)(Hout + (size_t)w * NFEAT + li * 8) = o0;
    *(float4*)(Hout + (size_t)w * NFEAT + li * 8 + 4) = o1;
  }
}

__global__ __launch_bounds__(256) void k_agg_readout(const __half* __restrict__ P,
                                                     const int* __restrict__ rs,
                                                     const int* __restrict__ csrc,
                                                     const float* __restrict__ cw,
                                                     const float* __restrict__ dis,
                                                     const float* __restrict__ bias,
                                                     const float* __restrict__ Wout,
                                                     const float* __restrict__ bout,
                                                     float* __restrict__ out, int N) {
  int w = (blockIdx.x * 256 + threadIdx.x) >> 6;
  if (w >= N) return;
  int lane = threadIdx.x & 63;
  int g = lane >> 4, li = lane & 15;
  float di = dis[w];
  float acc[8] = {0, 0, 0, 0, 0, 0, 0, 0};
  agg_body(P, rs, csrc, cw, di, w, g, li, acc);
  // all 64 lanes now hold the feature sums for block (lane&15)
  float4 b0 = *(const float4*)(bias + li * 8);
  float4 b1 = *(const float4*)(bias + li * 8 + 4);
  float4 w0 = *(const float4*)(Wout + li * 8);
  float4 w1 = *(const float4*)(Wout + li * 8 + 4);
  float p = 0.f;
  p = fmaf(fmaxf(acc[0] + b0.x, 0.f), w0.x, p);
  p = fmaf(fmaxf(acc[1] + b0.y, 0.f), w0.y, p);
  p = fmaf(fmaxf(acc[2] + b0.z, 0.f), w0.z, p);
  p = fmaf(fmaxf(acc[3] + b0.w, 0.f), w0.w, p);
  p = fmaf(fmaxf(acc[4] + b1.x, 0.f), w1.x, p);
  p = fmaf(fmaxf(acc[5] + b1.y, 0.f), w1.y, p);
  p = fmaf(fmaxf(acc[6] + b1.z, 0.f), w1.z, p);
  p = fmaf(fmaxf(acc[7] + b1.w, 0.f), w1.w, p);
  // sum the 16 feature-block partials (lanes 0..15; groups are duplicates)
  p += __shfl_down(p, 8, 64);
  p += __shfl_down(p, 4, 64);
  p += __shfl_down(p, 2, 64);
  p += __shfl_down(p, 1, 64);
  if (lane == 0) out[w] = p + bout[0];
}

// ---------------- launch ----------------

extern "C" void kernel_launch(void* const* d_in, const int* in_sizes, int n_in,
                              void* d_out, int out_size, void* d_ws, size_t ws_size,
                              hipStream_t stream) {
  const float* x    = (const float*)d_in[0];
  const int*   ei   = (const int*)d_in[1];
  const float* W1   = (const float*)d_in[2];
  const float* b1   = (const float*)d_in[3];
  const float* W2   = (const float*)d_in[4];
  const float* b2   = (const float*)d_in[5];
  const float* Wout = (const float*)d_in[6];
  const float* bout = (const float*)d_in[7];
  float* out = (float*)d_out;

  const int N = in_sizes[0] / NFEAT;
  const int E = in_sizes[1] / 2;
  const int* src = ei;
  const int* dst = ei + E;

  char* ws = (char*)d_ws;
  size_t off = 0;
  auto alloc = [&](size_t bytes) -> char* {
    char* p = ws + off;
    off = align_up(off + bytes, 256);
    return p;
  };
  float*  dis   = (float*)alloc((size_t)N * 4);
  int*    cnt   = (int*)alloc((size_t)N * 4);
  int*    rs    = (int*)alloc((size_t)(N + 1) * 4);
  int*    bsums = (int*)alloc(1024 * 4);
  int*    csrc  = (int*)alloc((size_t)E * 4);
  float*  cw    = (float*)alloc((size_t)E * 4);
  __half* P     = (__half*)alloc((size_t)N * NFEAT * 2);   // fp16 gather operand
  float*  H     = (float*)alloc((size_t)N * NFEAT * 4);    // fp32 hidden (gemm input)
  (void)ws_size; (void)n_in; (void)out_size;

  const int nbN = (N + 255) / 256;
  const int nbE = (E + 255) / 256;
  const int nbS = (N + 1023) / 1024;  // 98 for N=100000 (<=128 for k_scan2)

  hipMemsetAsync(cnt, 0, (size_t)N * 4, stream);
  k_count<<<nbE, 256, 0, stream>>>(dst, cnt, E);
  k_scan1<<<nbS, 256, 0, stream>>>(cnt, rs, bsums, dis, N);
  k_scan2<<<1, 128, 0, stream>>>(bsums, nbS);
  k_scan3<<<nbN, 256, 0, stream>>>(rs, bsums, cnt, N, E);
  k_fill<<<nbE, 256, 0, stream>>>(src, dst, rs, cnt, dis, csrc, cw, E);

  k_gemm<<<(N + 63) / 64, 256, 0, stream>>>(x, W1, P, N);
  k_agg_relu<<<(N + 3) / 4, 256, 0, stream>>>(P, rs, csrc, cw, dis, b1, H, N);
  k_gemm<<<(N + 63) / 64, 256, 0, stream>>>(H, W2, P, N);
  k_agg_readout<<<(N + 3) / 4, 256, 0, stream>>>(P, rs, csrc, cw, dis, b2, Wout, bout, out, N);
}

// Round 4
// 423.740 us; speedup vs baseline: 1.4370x; 1.0382x over previous
//
#include <hip/hip_runtime.h>
#include <hip/hip_fp16.h>
#include <type_traits>

#define NFEAT 128

static inline size_t align_up(size_t x, size_t a) { return (x + a - 1) & ~(a - 1); }

// ---------------- preprocessing: degree, CSR build ----------------

__global__ __launch_bounds__(256) void k_count(const int* __restrict__ dst,
                                               int* __restrict__ cnt, int E) {
  int e = blockIdx.x * 256 + threadIdx.x;
  if (e < E) atomicAdd(&cnt[dst[e]], 1);
}

// block-level exclusive scan, 1024 items/block (256 thr x 4)
__global__ __launch_bounds__(256) void k_scan1(const int* __restrict__ cnt,
                                               int* __restrict__ rs,
                                               int* __restrict__ bsums, int N) {
  __shared__ int sd[256];
  int tid = threadIdx.x;
  int base = blockIdx.x * 1024 + tid * 4;
  int v0 = 0, v1 = 0, v2 = 0, v3 = 0;
  if (base + 0 < N) v0 = cnt[base + 0];
  if (base + 1 < N) v1 = cnt[base + 1];
  if (base + 2 < N) v2 = cnt[base + 2];
  if (base + 3 < N) v3 = cnt[base + 3];
  int sum = v0 + v1 + v2 + v3;
  sd[tid] = sum;
  __syncthreads();
  for (int off = 1; off < 256; off <<= 1) {
    int t = (tid >= off) ? sd[tid - off] : 0;
    __syncthreads();
    sd[tid] += t;
    __syncthreads();
  }
  int run = sd[tid] - sum;  // exclusive prefix for this thread
  if (tid == 255) bsums[blockIdx.x] = sd[255];
  if (base + 0 < N) rs[base + 0] = run;
  run += v0;
  if (base + 1 < N) rs[base + 1] = run;
  run += v1;
  if (base + 2 < N) rs[base + 2] = run;
  run += v2;
  if (base + 3 < N) rs[base + 3] = run;
}

// scan of block sums (nb <= 128)
__global__ __launch_bounds__(128) void k_scan2(int* bsums, int nb) {
  __shared__ int sd[128];
  int tid = threadIdx.x;
  int v = (tid < nb) ? bsums[tid] : 0;
  sd[tid] = v;
  __syncthreads();
  for (int off = 1; off < 128; off <<= 1) {
    int t = (tid >= off) ? sd[tid - off] : 0;
    __syncthreads();
    sd[tid] += t;
    __syncthreads();
  }
  if (tid < nb) bsums[tid] = sd[tid] - v;  // exclusive
}

__global__ __launch_bounds__(256) void k_scan3(int* __restrict__ rs,
                                               const int* __restrict__ bsums,
                                               int N, int E) {
  int i = blockIdx.x * 256 + threadIdx.x;
  if (i < N) rs[i] += bsums[i >> 10];
  if (i == 0) rs[N] = E;
}

// single scattered 4B store per edge (cw eliminated by pre-scaling P rows by dis)
__global__ __launch_bounds__(256) void k_fill(const int* __restrict__ src,
                                              const int* __restrict__ dst,
                                              const int* __restrict__ rs,
                                              int* __restrict__ cur,
                                              int* __restrict__ csrc, int E) {
  int e = blockIdx.x * 256 + threadIdx.x;
  if (e >= E) return;
  int d = dst[e];
  int pos = rs[d] + atomicAdd(&cur[d], 1);
  csrc[pos] = src[e];
}

// ---------------- GEMM: P[N x128] = dis[i] * (X[N x128] @ W[128 x128]), fp16 out ----------------
// T = float (layer 1) or __half (layer 2, staging converts). Epilogue scales row by rsqrt(deg+1).

template <typename T>
__global__ __launch_bounds__(256) void k_gemm(const T* __restrict__ X,
                                              const float* __restrict__ W,
                                              const int* __restrict__ deg,
                                              __half* __restrict__ P, int N) {
  __shared__ float Xs[64][132];   // +4 pad
  __shared__ float Ws[64][128];
  const int tid = threadIdx.x;
  const int rowBase = blockIdx.x * 64;

  if constexpr (std::is_same_v<T, float>) {
    #pragma unroll
    for (int it = 0; it < 8; ++it) {
      int q = it * 256 + tid;        // 2048 float4 loads
      int r = q >> 5;
      int c = (q & 31) * 4;
      int gr = rowBase + r;
      float4 v = make_float4(0.f, 0.f, 0.f, 0.f);
      if (gr < N) v = *(const float4*)(X + (size_t)gr * NFEAT + c);
      *(float4*)&Xs[r][c] = v;
    }
  } else {
    #pragma unroll
    for (int it = 0; it < 4; ++it) {
      int q = it * 256 + tid;        // 1024 16B loads (8 halves each)
      int r = q >> 4;
      int c = (q & 15) * 8;
      int gr = rowBase + r;
      int4 raw = make_int4(0, 0, 0, 0);
      if (gr < N) raw = *(const int4*)(X + (size_t)gr * NFEAT + c);
      const __half2* h2 = (const __half2*)&raw;
      #pragma unroll
      for (int j = 0; j < 4; ++j) {
        float2 f = __half22float2(h2[j]);
        Xs[r][c + 2 * j] = f.x;
        Xs[r][c + 2 * j + 1] = f.y;
      }
    }
  }

  float acc[4][8];
  #pragma unroll
  for (int j = 0; j < 4; ++j)
    #pragma unroll
    for (int c = 0; c < 8; ++c) acc[j][c] = 0.f;

  const int cx = (tid & 15) * 8;
  const int r0 = (tid >> 4) * 4;

  for (int half = 0; half < 2; ++half) {
    __syncthreads();
    #pragma unroll
    for (int it = 0; it < 8; ++it) {
      int q = it * 256 + tid;
      int r = q >> 5;
      int c = (q & 31) * 4;
      *(float4*)&Ws[r][c] = *(const float4*)(W + (size_t)(half * 64 + r) * NFEAT + c);
    }
    __syncthreads();
    #pragma unroll 4
    for (int k = 0; k < 64; ++k) {
      float4 w0 = *(const float4*)&Ws[k][cx];
      float4 w1 = *(const float4*)&Ws[k][cx + 4];
      int kg = half * 64 + k;
      #pragma unroll
      for (int j = 0; j < 4; ++j) {
        float xv = Xs[r0 + j][kg];
        acc[j][0] = fmaf(xv, w0.x, acc[j][0]);
        acc[j][1] = fmaf(xv, w0.y, acc[j][1]);
        acc[j][2] = fmaf(xv, w0.z, acc[j][2]);
        acc[j][3] = fmaf(xv, w0.w, acc[j][3]);
        acc[j][4] = fmaf(xv, w1.x, acc[j][4]);
        acc[j][5] = fmaf(xv, w1.y, acc[j][5]);
        acc[j][6] = fmaf(xv, w1.z, acc[j][6]);
        acc[j][7] = fmaf(xv, w1.w, acc[j][7]);
      }
    }
  }

  #pragma unroll
  for (int j = 0; j < 4; ++j) {
    int gr = rowBase + r0 + j;
    if (gr < N) {
      float di = rsqrtf((float)deg[gr] + 1.0f);
      __half2 o[4];
      o[0] = __floats2half2_rn(di * acc[j][0], di * acc[j][1]);
      o[1] = __floats2half2_rn(di * acc[j][2], di * acc[j][3]);
      o[2] = __floats2half2_rn(di * acc[j][4], di * acc[j][5]);
      o[3] = __floats2half2_rn(di * acc[j][6], di * acc[j][7]);
      *(int4*)(P + (size_t)gr * NFEAT + cx) = *(const int4*)o;  // 8 halves = 16B
    }
  }
}

// ---------------- aggregation: one wave/node, 4 edge-groups x 16 lanes, 16B/lane ----------------
// Unweighted row-sum of pre-scaled P rows; final scale by dis_w (from CSR degree).

__device__ __forceinline__ float agg_body(const __half* __restrict__ P,
                                          const int* __restrict__ rs,
                                          const int* __restrict__ csrc,
                                          int w, int g, int li, float acc[8]) {
  int e0 = rs[w], e1 = rs[w + 1];
  float di = rsqrtf((float)(e1 - e0) + 1.0f);
  if (g == 0) {  // self loop: P'[w]
    int4 raw = *(const int4*)(P + (size_t)w * NFEAT + li * 8);
    const __half2* h2 = (const __half2*)&raw;
    #pragma unroll
    for (int j = 0; j < 4; ++j) {
      float2 f = __half22float2(h2[j]);
      acc[2 * j]     = f.x;
      acc[2 * j + 1] = f.y;
    }
  }
  for (int e = e0 + g; e < e1; e += 4) {
    int s = csrc[e];
    int4 raw = *(const int4*)(P + (size_t)s * NFEAT + li * 8);
    const __half2* h2 = (const __half2*)&raw;
    #pragma unroll
    for (int j = 0; j < 4; ++j) {
      float2 f = __half22float2(h2[j]);
      acc[2 * j]     += f.x;
      acc[2 * j + 1] += f.y;
    }
  }
  #pragma unroll
  for (int j = 0; j < 8; ++j) {
    float v = acc[j];
    v += __shfl_xor(v, 16, 64);
    v += __shfl_xor(v, 32, 64);
    acc[j] = v;
  }
  return di;
}

__global__ __launch_bounds__(256) void k_agg_relu(const __half* __restrict__ P,
                                                  const int* __restrict__ rs,
                                                  const int* __restrict__ csrc,
                                                  const float* __restrict__ bias,
                                                  __half* __restrict__ Hout, int N) {
  int w = (blockIdx.x * 256 + threadIdx.x) >> 6;
  if (w >= N) return;
  int lane = threadIdx.x & 63;
  int g = lane >> 4, li = lane & 15;
  float acc[8] = {0, 0, 0, 0, 0, 0, 0, 0};
  float di = agg_body(P, rs, csrc, w, g, li, acc);
  if (g == 0) {
    float4 b0 = *(const float4*)(bias + li * 8);
    float4 b1 = *(const float4*)(bias + li * 8 + 4);
    __half2 o[4];
    o[0] = __floats2half2_rn(fmaxf(fmaf(di, acc[0], b0.x), 0.f),
                             fmaxf(fmaf(di, acc[1], b0.y), 0.f));
    o[1] = __floats2half2_rn(fmaxf(fmaf(di, acc[2], b0.z), 0.f),
                             fmaxf(fmaf(di, acc[3], b0.w), 0.f));
    o[2] = __floats2half2_rn(fmaxf(fmaf(di, acc[4], b1.x), 0.f),
                             fmaxf(fmaf(di, acc[5], b1.y), 0.f));
    o[3] = __floats2half2_rn(fmaxf(fmaf(di, acc[6], b1.z), 0.f),
                             fmaxf(fmaf(di, acc[7], b1.w), 0.f));
    *(int4*)(Hout + (size_t)w * NFEAT + li * 8) = *(const int4*)o;
  }
}

__global__ __launch_bounds__(256) void k_agg_readout(const __half* __restrict__ P,
                                                     const int* __restrict__ rs,
                                                     const int* __restrict__ csrc,
                                                     const float* __restrict__ bias,
                                                     const float* __restrict__ Wout,
                                                     const float* __restrict__ bout,
                                                     float* __restrict__ out, int N) {
  int w = (blockIdx.x * 256 + threadIdx.x) >> 6;
  if (w >= N) return;
  int lane = threadIdx.x & 63;
  int g = lane >> 4, li = lane & 15;
  float acc[8] = {0, 0, 0, 0, 0, 0, 0, 0};
  float di = agg_body(P, rs, csrc, w, g, li, acc);
  float4 b0 = *(const float4*)(bias + li * 8);
  float4 b1 = *(const float4*)(bias + li * 8 + 4);
  float4 w0 = *(const float4*)(Wout + li * 8);
  float4 w1 = *(const float4*)(Wout + li * 8 + 4);
  float p = 0.f;
  p = fmaf(fmaxf(fmaf(di, acc[0], b0.x), 0.f), w0.x, p);
  p = fmaf(fmaxf(fmaf(di, acc[1], b0.y), 0.f), w0.y, p);
  p = fmaf(fmaxf(fmaf(di, acc[2], b0.z), 0.f), w0.z, p);
  p = fmaf(fmaxf(fmaf(di, acc[3], b0.w), 0.f), w0.w, p);
  p = fmaf(fmaxf(fmaf(di, acc[4], b1.x), 0.f), w1.x, p);
  p = fmaf(fmaxf(fmaf(di, acc[5], b1.y), 0.f), w1.y, p);
  p = fmaf(fmaxf(fmaf(di, acc[6], b1.z), 0.f), w1.z, p);
  p = fmaf(fmaxf(fmaf(di, acc[7], b1.w), 0.f), w1.w, p);
  p += __shfl_down(p, 8, 64);
  p += __shfl_down(p, 4, 64);
  p += __shfl_down(p, 2, 64);
  p += __shfl_down(p, 1, 64);
  if (lane == 0) out[w] = p + bout[0];
}

// ---------------- launch ----------------

extern "C" void kernel_launch(void* const* d_in, const int* in_sizes, int n_in,
                              void* d_out, int out_size, void* d_ws, size_t ws_size,
                              hipStream_t stream) {
  const float* x    = (const float*)d_in[0];
  const int*   ei   = (const int*)d_in[1];
  const float* W1   = (const float*)d_in[2];
  const float* b1   = (const float*)d_in[3];
  const float* W2   = (const float*)d_in[4];
  const float* b2   = (const float*)d_in[5];
  const float* Wout = (const float*)d_in[6];
  const float* bout = (const float*)d_in[7];
  float* out = (float*)d_out;

  const int N = in_sizes[0] / NFEAT;
  const int E = in_sizes[1] / 2;
  const int* src = ei;
  const int* dst = ei + E;

  char* ws = (char*)d_ws;
  size_t off = 0;
  auto alloc = [&](size_t bytes) -> char* {
    char* p = ws + off;
    off = align_up(off + bytes, 256);
    return p;
  };
  int*    cnt   = (int*)alloc((size_t)N * 4);        // in-degree (kept for epilogue dis)
  int*    cur   = (int*)alloc((size_t)N * 4);        // fill cursor
  int*    rs    = (int*)alloc((size_t)(N + 1) * 4);
  int*    bsums = (int*)alloc(1024 * 4);
  int*    csrc  = (int*)alloc((size_t)E * 4);
  __half* P     = (__half*)alloc((size_t)N * NFEAT * 2);  // pre-scaled gather operand
  __half* H     = (__half*)alloc((size_t)N * NFEAT * 2);  // hidden activations (fp16)
  (void)ws_size; (void)n_in; (void)out_size;

  const int nbN = (N + 255) / 256;
  const int nbE = (E + 255) / 256;
  const int nbS = (N + 1023) / 1024;  // 98 for N=100000 (<=128 for k_scan2)

  hipMemsetAsync(cnt, 0, (size_t)N * 4, stream);
  hipMemsetAsync(cur, 0, (size_t)N * 4, stream);
  k_count<<<nbE, 256, 0, stream>>>(dst, cnt, E);
  k_scan1<<<nbS, 256, 0, stream>>>(cnt, rs, bsums, N);
  k_scan2<<<1, 128, 0, stream>>>(bsums, nbS);
  k_scan3<<<nbN, 256, 0, stream>>>(rs, bsums, N, E);
  k_fill<<<nbE, 256, 0, stream>>>(src, dst, rs, cur, csrc, E);

  k_gemm<float><<<(N + 63) / 64, 256, 0, stream>>>(x, W1, cnt, P, N);
  k_agg_relu<<<(N + 3) / 4, 256, 0, stream>>>(P, rs, csrc, b1, H, N);
  k_gemm<__half><<<(N + 63) / 64, 256, 0, stream>>>(H, W2, cnt, P, N);
  k_agg_readout<<<(N + 3) / 4, 256, 0, stream>>>(P, rs, csrc, b2, Wout, bout, out, N);
}